// Round 1
// 740.765 us; speedup vs baseline: 1.1589x; 1.1589x over previous
//
#include <hip/hip_runtime.h>
#include <hip/hip_bf16.h>
#include <math.h>

#define T_TOK 8192
#define HDIM  1024
#define IDIM  4096
#define SDIM  128
#define TOPK  16

typedef __bf16 bf16x8 __attribute__((ext_vector_type(8)));
typedef float  f32x4  __attribute__((ext_vector_type(4)));

__device__ __forceinline__ unsigned short f2bf(float f) {
    union { float f; unsigned u; } a; a.f = f;
    unsigned r = a.u + 0x7fffu + ((a.u >> 16) & 1u);
    return (unsigned short)(r >> 16);
}
__device__ __forceinline__ float bf2f(unsigned short b) {
    union { unsigned u; float f; } a; a.u = ((unsigned)b) << 16;
    return a.f;
}

__device__ __forceinline__ void gld_lds16(const void* g, void* l) {
    __builtin_amdgcn_global_load_lds(
        (__attribute__((address_space(1))) void*)g,
        (__attribute__((address_space(3))) void*)l,
        16, 0, 0);
}

// ---------------- merged fp32 -> bf16 convert over 8 segments ----------------
struct CvtSegs {
    const float4* src[8];
    ushort4*      dst[8];
    int           end[8];   // prefix-sum of float4 counts
};

__global__ __launch_bounds__(256)
void cvt_all_kernel(CvtSegs segs) {
    int i = blockIdx.x * 256 + threadIdx.x;
    if (i >= segs.end[7]) return;
    int s = 0;
    #pragma unroll
    for (int k = 0; k < 7; ++k) s += (i >= segs.end[k]) ? 1 : 0;
    int base = (s == 0) ? 0 : segs.end[s - 1];
    int j = i - base;
    float4 v = segs.src[s][j];
    ushort4 o;
    o.x = f2bf(v.x); o.y = f2bf(v.y); o.z = f2bf(v.z); o.w = f2bf(v.w);
    segs.dst[s][j] = o;
}

// ---------------- generic C = A * B^T (bf16 in, fp32 out), 128x128 tile ----------------
template<int ADD>
__global__ __launch_bounds__(256)
void gemm_bt(const unsigned short* __restrict__ A, const unsigned short* __restrict__ B,
             float* __restrict__ C, int M, int N, int K) {
    __shared__ unsigned short As[4096];  // [kc=4][m=128][8] bf16
    __shared__ unsigned short Bs[4096];  // [kc=4][n=128][8]
    const int tid  = threadIdx.x;
    const int lane = tid & 63;
    const int wave = tid >> 6;
    const int tm = blockIdx.x * 128;
    const int tn = blockIdx.y * 128;
    const int wm = (wave & 1) * 64;
    const int wn = (wave >> 1) * 64;
    const int quad = lane >> 4;
    const int tr   = lane & 15;

    f32x4 acc[4][4] = {};
    bf16x8 af[4], bfr[4];

    const int ua0 = tid,        am0 = ua0 & 127, ak0 = ua0 >> 7;
    const int ua1 = tid + 256,  am1 = ua1 & 127, ak1 = ua1 >> 7;

    auto issue = [&](int kt) {
        gld_lds16(A + (size_t)(tm + am0) * K + kt + ak0 * 8, &As[ua0 * 8]);
        gld_lds16(A + (size_t)(tm + am1) * K + kt + ak1 * 8, &As[ua1 * 8]);
        gld_lds16(B + (size_t)(tn + am0) * K + kt + ak0 * 8, &Bs[ua0 * 8]);
        gld_lds16(B + (size_t)(tn + am1) * K + kt + ak1 * 8, &Bs[ua1 * 8]);
    };
    auto rdfrags = [&]() {
        #pragma unroll
        for (int mi = 0; mi < 4; ++mi)
            af[mi] = *(const bf16x8*)&As[(quad * 128 + wm + mi * 16 + tr) * 8];
        #pragma unroll
        for (int ni = 0; ni < 4; ++ni)
            bfr[ni] = *(const bf16x8*)&Bs[(quad * 128 + wn + ni * 16 + tr) * 8];
    };
    auto mfmas = [&]() {
        #pragma unroll
        for (int mi = 0; mi < 4; ++mi)
            #pragma unroll
            for (int ni = 0; ni < 4; ++ni)
                acc[mi][ni] = __builtin_amdgcn_mfma_f32_16x16x32_bf16(af[mi], bfr[ni], acc[mi][ni], 0, 0, 0);
    };

    issue(0);
    asm volatile("s_waitcnt vmcnt(0)" ::: "memory");
    __syncthreads();
    rdfrags();
    for (int kt = 32; kt < K; kt += 32) {
        __syncthreads();
        issue(kt);
        mfmas();
        asm volatile("s_waitcnt vmcnt(0)" ::: "memory");
        __syncthreads();
        rdfrags();
    }
    mfmas();

    #pragma unroll
    for (int mi = 0; mi < 4; ++mi) {
        #pragma unroll
        for (int ni = 0; ni < 4; ++ni) {
            int col = tn + wn + ni * 16 + tr;
            #pragma unroll
            for (int r = 0; r < 4; ++r) {
                int row = tm + wm + mi * 16 + quad * 4 + r;
                size_t o = (size_t)row * N + col;
                float v = acc[mi][ni][r];
                if (ADD) v += C[o];
                C[o] = v;
            }
        }
    }
}

// ---------------- fused GEMM1, 256x256 tile, 8-phase counted-vmcnt schedule ----------------
// h = silu(x @ Wg^T) * (x @ Wu^T), bf16 out.
// Virtual concatenated weight Wcat[8192][1024]: row r -> (((r>>4)&1)? Wu : Wg) row ((r>>5)<<4 | (r&15)),
// i.e. 16-row groups alternate gate/up so n-frag pairs (2p, 2p+1) hold (gate,up) for the SAME
// intermediate columns in the SAME lane -> zero-shuffle SwiGLU epilogue.
//
// LDS ring: per operand 4 half-tile slots (2 tile-parities x 2 k-halves), slot = 256 rows x 32 cols bf16
// = 16KB, packed as row-pairs in 128B lines with XOR swizzle:
//   slotoff(row,cq) = (row>>1)*128 + ((((row&1)<<2)|cq) ^ ((row>>1)&7))*16
// -> global_load_lds dest stays linear (source pre-permuted), ds_read_b128 conflict-free.
// Counted vmcnt: 2 gld_lds/wave/phase, vmcnt(4) twice per K-tile; every half-tile first consumed
// >=3 phases after issue. Raw s_barrier (no vmcnt(0) drain).
#define BARX() asm volatile("s_barrier" ::: "memory")
#define VMW4() asm volatile("s_waitcnt vmcnt(4)" ::: "memory")

#define RD_A(par, ks, MB) { const char* _p = lds + ((par) << 15) + ((ks) << 14); \
    af[0] = *(const bf16x8*)(_p + aoff[(MB)+0]); \
    af[1] = *(const bf16x8*)(_p + aoff[(MB)+1]); \
    af[2] = *(const bf16x8*)(_p + aoff[(MB)+2]); \
    af[3] = *(const bf16x8*)(_p + aoff[(MB)+3]); }

#define RD_B(par, ks) { const char* _p = lds + 65536 + ((par) << 15) + ((ks) << 14); \
    bfv[0] = *(const bf16x8*)(_p + boff[0]); \
    bfv[1] = *(const bf16x8*)(_p + boff[1]); \
    bfv[2] = *(const bf16x8*)(_p + boff[2]); \
    bfv[3] = *(const bf16x8*)(_p + boff[3]); }

#define MMA16(ACC) { __builtin_amdgcn_s_setprio(1); \
    _Pragma("unroll") \
    for (int _i = 0; _i < 4; ++_i) \
        _Pragma("unroll") \
        for (int _n = 0; _n < 4; ++_n) \
            ACC[_i][_n] = __builtin_amdgcn_mfma_f32_16x16x32_bf16(af[_i], bfv[_n], ACC[_i][_n], 0, 0, 0); \
    __builtin_amdgcn_s_setprio(0); }

__global__ __launch_bounds__(512, 2)
void gemm1_8ph(const unsigned short* __restrict__ Xb, const unsigned short* __restrict__ Wg,
               const unsigned short* __restrict__ Wu, unsigned short* __restrict__ Hb) {
    __shared__ __align__(16) char lds[131072];
    const int tid  = threadIdx.x;
    const int lane = tid & 63;
    const int wid  = tid >> 6;
    const int quad = lane >> 4;
    const int tr   = lane & 15;
    const int wm   = (wid >> 2) << 7;   // 0 / 128
    const int wn   = (wid & 3) << 6;    // 0 / 64 / 128 / 192

    // XCD-aware swizzle: 1024 blocks, 8 XCDs -> 128 contiguous ids per XCD (bijective).
    const int bid = blockIdx.x;
    const int swz = (bid & 7) * 128 + (bid >> 3);
    const int gm  = (swz & 31) << 8;    // token-row base
    const int gn  = (swz >> 5) << 8;    // Wcat-row base (XCD-local B panel = 2MB -> L2-resident)

    // staging thread map (inverse of the LDS swizzle, so gld_lds dest stays linear)
    const int vsw  = (tid & 7) ^ ((tid >> 3) & 7);
    const int rowb = ((tid >> 3) << 1) | (vsw >> 2);   // 0..127
    const int cq8  = (vsw & 3) << 3;                   // element offset within k-half

    const unsigned short* pA0 = Xb + (size_t)(gm + rowb) * HDIM + cq8;
    const unsigned short* pA1 = pA0 + (size_t)128 * HDIM;
    auto wsrc = [&](int R) -> const unsigned short* {
        const unsigned short* base = ((R >> 4) & 1) ? Wu : Wg;
        int sr = ((R >> 5) << 4) | (R & 15);
        return base + (size_t)sr * HDIM + cq8;
    };
    const unsigned short* pB0 = wsrc(gn + rowb);
    const unsigned short* pB1 = wsrc(gn + rowb + 128);

    int aoff[8], boff[4];
    #pragma unroll
    for (int i = 0; i < 8; ++i) {
        int row = wm + i * 16 + tr;
        aoff[i] = ((row >> 1) << 7) | (((((row & 1) << 2) | quad) ^ ((row >> 1) & 7)) << 4);
    }
    #pragma unroll
    for (int i = 0; i < 4; ++i) {
        int row = wn + i * 16 + tr;
        boff[i] = ((row >> 1) << 7) | (((((row & 1) << 2) | quad) ^ ((row >> 1) & 7)) << 4);
    }

    f32x4 accL[4][4] = {};   // mi 0..3
    f32x4 accH[4][4] = {};   // mi 4..7
    bf16x8 af[4], bfv[4];

    auto stageA = [&](int nxt, int ks, int kOff) {
        char* d = lds + (nxt << 15) + (ks << 14) + (tid << 4);
        gld_lds16(pA0 + kOff, d);
        gld_lds16(pA1 + kOff, d + 8192);
    };
    auto stageB = [&](int nxt, int ks, int kOff) {
        char* d = lds + 65536 + (nxt << 15) + (ks << 14) + (tid << 4);
        gld_lds16(pB0 + kOff, d);
        gld_lds16(pB1 + kOff, d + 8192);
    };

    // prologue: stage tile 0 fully, drain once
    stageA(0, 0, 0);  stageB(0, 0, 0);
    stageA(0, 1, 32); stageB(0, 1, 32);
    asm volatile("s_waitcnt vmcnt(0)" ::: "memory");
    BARX();

    for (int t = 0; t < 16; ++t) {
        const int par = t & 1, nxt = par ^ 1;
        const int kN = (t < 15 ? t + 1 : 15) << 6;   // clamped prefetch (keeps vmcnt counts exact)
        // P0: ks0, mi0-3
        RD_A(par, 0, 0); RD_B(par, 0);
        stageA(nxt, 0, kN);
        BARX();
        MMA16(accL);
        BARX();
        // P1: ks0, mi4-7
        RD_A(par, 0, 4);
        stageB(nxt, 0, kN);
        VMW4(); BARX();
        MMA16(accH);
        BARX();
        // P2: ks1, mi0-3
        RD_A(par, 1, 0); RD_B(par, 1);
        stageA(nxt, 1, kN + 32);
        BARX();
        MMA16(accL);
        BARX();
        // P3: ks1, mi4-7
        RD_A(par, 1, 4);
        stageB(nxt, 1, kN + 32);
        VMW4(); BARX();
        MMA16(accH);
        BARX();
    }
    asm volatile("s_waitcnt vmcnt(0)" ::: "memory");  // drain DMA before block retires

    // SwiGLU epilogue: frag pair (2p, 2p+1) = (gate, up) for intermediate cols ((gn+wn)>>1 + 16p + tr)
    const size_t icb = (size_t)((gn + wn) >> 1) + tr;
    const int rbase = gm + wm + quad * 4;
    #pragma unroll
    for (int mi = 0; mi < 4; ++mi) {
        #pragma unroll
        for (int p = 0; p < 2; ++p) {
            #pragma unroll
            for (int r = 0; r < 4; ++r) {
                {
                    float g = accL[mi][2 * p][r], u = accL[mi][2 * p + 1][r];
                    float h = g / (1.0f + __expf(-g)) * u;
                    Hb[(size_t)(rbase + mi * 16 + r) * IDIM + icb + 16 * p] = f2bf(h);
                }
                {
                    float g = accH[mi][2 * p][r], u = accH[mi][2 * p + 1][r];
                    float h = g / (1.0f + __expf(-g)) * u;
                    Hb[(size_t)(rbase + 64 + mi * 16 + r) * IDIM + icb + 16 * p] = f2bf(h);
                }
            }
        }
    }
}

// ---------------- batchnorm stats ----------------
__global__ void bn_stats(const float* __restrict__ gxy, float* __restrict__ sums, float* __restrict__ ssq) {
    const int j = threadIdx.x;
    const int b = blockIdx.x;
    float s = 0.f, q = 0.f;
    for (int r = 0; r < 32; ++r) {
        float v = gxy[(size_t)(b * 32 + r) * 256 + j];
        s += v; q += v * v;
    }
    atomicAdd(&sums[j], s);
    atomicAdd(&ssq[j], q);
}

// ---------------- routing: bn -> log_softmax -> top16 via candidate reduction ----------------
__global__ __launch_bounds__(256)
void routing_kernel(const float* __restrict__ gxy, const float* __restrict__ sums,
                    const float* __restrict__ ssq, int* __restrict__ oidx, float* __restrict__ owt) {
    const int lane = threadIdx.x & 63;
    const int t = blockIdx.x * 4 + (threadIdx.x >> 6);
    const float invT = 1.0f / (float)T_TOK;
    const float* g = gxy + (size_t)t * 256;

    float z[4];
    const int cols[4] = {lane, lane + 64, 128 + lane, 192 + lane};
    #pragma unroll
    for (int i = 0; i < 4; ++i) {
        int c = cols[i];
        float mu  = sums[c] * invT;
        float var = ssq[c] * invT - mu * mu;
        z[i] = (g[c] - mu) * rsqrtf(var + 1e-5f);
    }
    float mx = fmaxf(z[0], z[1]);
    float my = fmaxf(z[2], z[3]);
    #pragma unroll
    for (int m = 32; m >= 1; m >>= 1) {
        mx = fmaxf(mx, __shfl_xor(mx, m));
        my = fmaxf(my, __shfl_xor(my, m));
    }
    float sx = __expf(z[0] - mx) + __expf(z[1] - mx);
    float sy = __expf(z[2] - my) + __expf(z[3] - my);
    #pragma unroll
    for (int m = 32; m >= 1; m >>= 1) {
        sx += __shfl_xor(sx, m);
        sy += __shfl_xor(sy, m);
    }
    float lx0 = z[0] - (mx + __logf(sx)), lx1 = z[1] - (mx + __logf(sx));
    float ly0 = z[2] - (my + __logf(sy)), ly1 = z[3] - (my + __logf(sy));

    float aw = -INFINITY; int ai = 0;
    float bw = -INFINITY; int bi = 0;
    {
        float v0 = lx0, v1 = lx1;
        for (int i = 0; i < 16; ++i) {
            float v; int c;
            if (v0 >= v1) { v = v0; c = lane; } else { v = v1; c = lane + 64; }
            #pragma unroll
            for (int m = 32; m >= 1; m >>= 1) {
                float ov = __shfl_xor(v, m); int oc = __shfl_xor(c, m);
                if (ov > v || (ov == v && oc < c)) { v = ov; c = oc; }
            }
            if ((c & 63) == lane) { if (c < 64) v0 = -INFINITY; else v1 = -INFINITY; }
            if (lane == i) { aw = v; ai = c; }
        }
    }
    {
        float v0 = ly0, v1 = ly1;
        for (int i = 0; i < 16; ++i) {
            float v; int c;
            if (v0 >= v1) { v = v0; c = lane; } else { v = v1; c = lane + 64; }
            #pragma unroll
            for (int m = 32; m >= 1; m >>= 1) {
                float ov = __shfl_xor(v, m); int oc = __shfl_xor(c, m);
                if (ov > v || (ov == v && oc < c)) { v = ov; c = oc; }
            }
            if ((c & 63) == lane) { if (c < 64) v0 = -INFINITY; else v1 = -INFINITY; }
            if (lane == i) { bw = v; bi = c; }
        }
    }
    float cv[4];
    #pragma unroll
    for (int j = 0; j < 4; ++j) {
        int c = lane + 64 * j;
        cv[j] = __shfl(aw, c >> 4) + __shfl(bw, c & 15);
    }
    int myidx = 0; float myw = 0.f;
    for (int i = 0; i < 16; ++i) {
        float v = cv[0]; int c = lane;
        #pragma unroll
        for (int j = 1; j < 4; ++j) { int cc = lane + 64 * j; if (cv[j] > v) { v = cv[j]; c = cc; } }
        #pragma unroll
        for (int m = 32; m >= 1; m >>= 1) {
            float ov = __shfl_xor(v, m); int oc = __shfl_xor(c, m);
            if (ov > v || (ov == v && oc < c)) { v = ov; c = oc; }
        }
        #pragma unroll
        for (int j = 0; j < 4; ++j) if (c == lane + 64 * j) cv[j] = -INFINITY;
        int p = c >> 4, q = c & 15;
        int ex = __shfl(ai, p);
        int ey = __shfl(bi, q);
        if (lane == i) { myidx = ex * 128 + ey; myw = __expf(v); }
    }
    if (lane < 16) {
        oidx[t * TOPK + lane] = myidx;
        owt[t * TOPK + lane]  = myw;
    }
}

// ---------------- expert gather/combine (bf16 tables + bf16 x) ----------------
__global__ __launch_bounds__(256)
void expert_combine(const unsigned short* __restrict__ xb, const int* __restrict__ idx,
                    const float* __restrict__ wts, const unsigned short* __restrict__ ueb,
                    const unsigned short* __restrict__ deb, float* __restrict__ out) {
    const int t = blockIdx.x;
    const int tid = threadIdx.x;
    const int lane = tid & 63, wv = tid >> 6;
    __shared__ float part[TOPK * 4];
    __shared__ float sc[TOPK];
    ushort4 xv4 = ((const ushort4*)(xb + (size_t)t * HDIM))[tid];
    float x0 = bf2f(xv4.x), x1 = bf2f(xv4.y), x2 = bf2f(xv4.z), x3 = bf2f(xv4.w);
    int e[TOPK];
    #pragma unroll
    for (int k = 0; k < TOPK; ++k) e[k] = idx[t * TOPK + k];
    #pragma unroll
    for (int k = 0; k < TOPK; ++k) {
        ushort4 u4 = ((const ushort4*)(ueb + (size_t)e[k] * HDIM))[tid];
        float p = bf2f(u4.x) * x0 + bf2f(u4.y) * x1 + bf2f(u4.z) * x2 + bf2f(u4.w) * x3;
        #pragma unroll
        for (int m = 32; m >= 1; m >>= 1) p += __shfl_xor(p, m);
        if (lane == 0) part[k * 4 + wv] = p;
    }
    __syncthreads();
    if (tid < TOPK) {
        float s = part[tid * 4] + part[tid * 4 + 1] + part[tid * 4 + 2] + part[tid * 4 + 3];
        sc[tid] = s * wts[t * TOPK + tid];
    }
    __syncthreads();
    float4 acc = {0.f, 0.f, 0.f, 0.f};
    #pragma unroll
    for (int k = 0; k < TOPK; ++k) {
        float s = sc[k];
        ushort4 d4 = ((const ushort4*)(deb + (size_t)e[k] * HDIM))[tid];
        acc.x += s * bf2f(d4.x); acc.y += s * bf2f(d4.y);
        acc.z += s * bf2f(d4.z); acc.w += s * bf2f(d4.w);
    }
    ((float4*)(out + (size_t)t * HDIM))[tid] = acc;
}

extern "C" void kernel_launch(void* const* d_in, const int* in_sizes, int n_in,
                              void* d_out, int out_size, void* d_ws, size_t ws_size,
                              hipStream_t stream) {
    const float* x  = (const float*)d_in[0];
    const float* gw = (const float*)d_in[1];
    const float* uw = (const float*)d_in[2];
    const float* dw = (const float*)d_in[3];
    const float* wx = (const float*)d_in[4];
    const float* wy = (const float*)d_in[5];
    const float* ue = (const float*)d_in[6];
    const float* de = (const float*)d_in[7];
    float* out = (float*)d_out;

    char* ws = (char*)d_ws;
    size_t o = 0;
    auto alloc = [&](size_t bytes) { void* p = ws + o; o += (bytes + 255) & ~(size_t)255; return p; };
    unsigned short* xb    = (unsigned short*)alloc((size_t)T_TOK * HDIM * 2);
    unsigned short* gateb = (unsigned short*)alloc((size_t)IDIM * HDIM * 2);
    unsigned short* upb   = (unsigned short*)alloc((size_t)IDIM * HDIM * 2);
    unsigned short* downb = (unsigned short*)alloc((size_t)HDIM * IDIM * 2);
    unsigned short* wrb   = (unsigned short*)alloc((size_t)256 * HDIM * 2);
    unsigned short* ueb   = (unsigned short*)alloc((size_t)16384 * HDIM * 2);
    unsigned short* deb   = (unsigned short*)alloc((size_t)16384 * HDIM * 2);
    unsigned short* hbuf  = (unsigned short*)alloc((size_t)T_TOK * IDIM * 2);
    float* gxy  = (float*)alloc((size_t)T_TOK * 256 * 4);
    float* sums = (float*)alloc(256 * 4);
    float* ssq  = (float*)alloc(256 * 4);
    int*   idxs = (int*)alloc((size_t)T_TOK * TOPK * 4);
    float* wts  = (float*)alloc((size_t)T_TOK * TOPK * 4);

    // merged converts (8 segments)
    CvtSegs segs;
    const float* srcs[8] = {x, gw, uw, dw, wx, wy, ue, de};
    unsigned short* dsts[8] = {xb, gateb, upb, downb, wrb, wrb + SDIM * HDIM, ueb, deb};
    const int cnt4[8] = {T_TOK * HDIM / 4, IDIM * HDIM / 4, IDIM * HDIM / 4, IDIM * HDIM / 4,
                         SDIM * HDIM / 4, SDIM * HDIM / 4, 16384 * HDIM / 4, 16384 * HDIM / 4};
    int acc = 0;
    for (int i = 0; i < 8; ++i) {
        segs.src[i] = (const float4*)srcs[i];
        segs.dst[i] = (ushort4*)dsts[i];
        acc += cnt4[i];
        segs.end[i] = acc;
    }
    cvt_all_kernel<<<(acc + 255) / 256, 256, 0, stream>>>(segs);

    // router logits: gxy[T,256] = xb @ wrb^T
    hipMemsetAsync(sums, 0, 2 * 256 * 4, stream);  // sums+ssq contiguous
    gemm_bt<0><<<dim3(T_TOK / 128, 256 / 128), 256, 0, stream>>>(xb, wrb, gxy, T_TOK, 256, HDIM);
    bn_stats<<<256, 256, 0, stream>>>(gxy, sums, ssq);
    routing_kernel<<<T_TOK / 4, 256, 0, stream>>>(gxy, sums, ssq, idxs, wts);

    // expert branch writes out fully
    expert_combine<<<T_TOK, 256, 0, stream>>>(xb, idxs, wts, ueb, deb, out);

    // MLP branch: fused gate/up 8-phase GEMM, then down-proj accumulate
    gemm1_8ph<<<1024, 512, 0, stream>>>(xb, gateb, upb, hbuf);
    gemm_bt<1><<<dim3(T_TOK / 128, HDIM / 128), 256, 0, stream>>>(hbuf, downb, out, T_TOK, HDIM, IDIM);
}

// Round 3
// 690.429 us; speedup vs baseline: 1.2434x; 1.0729x over previous
//
#include <hip/hip_runtime.h>
#include <hip/hip_bf16.h>
#include <math.h>

#define T_TOK 8192
#define HDIM  1024
#define IDIM  4096
#define SDIM  128
#define TOPK  16

typedef __bf16 bf16x8 __attribute__((ext_vector_type(8)));
typedef float  f32x4  __attribute__((ext_vector_type(4)));

__device__ __forceinline__ unsigned short f2bf(float f) {
    union { float f; unsigned u; } a; a.f = f;
    unsigned r = a.u + 0x7fffu + ((a.u >> 16) & 1u);
    return (unsigned short)(r >> 16);
}
__device__ __forceinline__ float bf2f(unsigned short b) {
    union { unsigned u; float f; } a; a.u = ((unsigned)b) << 16;
    return a.f;
}

__device__ __forceinline__ void gld_lds16(const void* g, void* l) {
    __builtin_amdgcn_global_load_lds(
        (__attribute__((address_space(1))) void*)g,
        (__attribute__((address_space(3))) void*)l,
        16, 0, 0);
}

// ---------------- merged fp32 -> bf16 convert over 8 segments ----------------
struct CvtSegs {
    const float4* src[8];
    ushort4*      dst[8];
    int           end[8];   // prefix-sum of float4 counts
};

__global__ __launch_bounds__(256)
void cvt_all_kernel(CvtSegs segs) {
    int i = blockIdx.x * 256 + threadIdx.x;
    if (i >= segs.end[7]) return;
    int s = 0;
    #pragma unroll
    for (int k = 0; k < 7; ++k) s += (i >= segs.end[k]) ? 1 : 0;
    int base = (s == 0) ? 0 : segs.end[s - 1];
    int j = i - base;
    float4 v = segs.src[s][j];
    ushort4 o;
    o.x = f2bf(v.x); o.y = f2bf(v.y); o.z = f2bf(v.z); o.w = f2bf(v.w);
    segs.dst[s][j] = o;
}

// ---------------- generic C = A * B^T (bf16 in, fp32 out), 128x128 tile ----------------
// (kept only for the small router GEMM)
template<int ADD>
__global__ __launch_bounds__(256)
void gemm_bt(const unsigned short* __restrict__ A, const unsigned short* __restrict__ B,
             float* __restrict__ C, int M, int N, int K) {
    __shared__ unsigned short As[4096];  // [kc=4][m=128][8] bf16
    __shared__ unsigned short Bs[4096];  // [kc=4][n=128][8]
    const int tid  = threadIdx.x;
    const int lane = tid & 63;
    const int wave = tid >> 6;
    const int tm = blockIdx.x * 128;
    const int tn = blockIdx.y * 128;
    const int wm = (wave & 1) * 64;
    const int wn = (wave >> 1) * 64;
    const int quad = lane >> 4;
    const int tr   = lane & 15;

    f32x4 acc[4][4] = {};
    bf16x8 af[4], bfr[4];

    const int ua0 = tid,        am0 = ua0 & 127, ak0 = ua0 >> 7;
    const int ua1 = tid + 256,  am1 = ua1 & 127, ak1 = ua1 >> 7;

    auto issue = [&](int kt) {
        gld_lds16(A + (size_t)(tm + am0) * K + kt + ak0 * 8, &As[ua0 * 8]);
        gld_lds16(A + (size_t)(tm + am1) * K + kt + ak1 * 8, &As[ua1 * 8]);
        gld_lds16(B + (size_t)(tn + am0) * K + kt + ak0 * 8, &Bs[ua0 * 8]);
        gld_lds16(B + (size_t)(tn + am1) * K + kt + ak1 * 8, &Bs[ua1 * 8]);
    };
    auto rdfrags = [&]() {
        #pragma unroll
        for (int mi = 0; mi < 4; ++mi)
            af[mi] = *(const bf16x8*)&As[(quad * 128 + wm + mi * 16 + tr) * 8];
        #pragma unroll
        for (int ni = 0; ni < 4; ++ni)
            bfr[ni] = *(const bf16x8*)&Bs[(quad * 128 + wn + ni * 16 + tr) * 8];
    };
    auto mfmas = [&]() {
        #pragma unroll
        for (int mi = 0; mi < 4; ++mi)
            #pragma unroll
            for (int ni = 0; ni < 4; ++ni)
                acc[mi][ni] = __builtin_amdgcn_mfma_f32_16x16x32_bf16(af[mi], bfr[ni], acc[mi][ni], 0, 0, 0);
    };

    issue(0);
    asm volatile("s_waitcnt vmcnt(0)" ::: "memory");
    __syncthreads();
    rdfrags();
    for (int kt = 32; kt < K; kt += 32) {
        __syncthreads();
        issue(kt);
        mfmas();
        asm volatile("s_waitcnt vmcnt(0)" ::: "memory");
        __syncthreads();
        rdfrags();
    }
    mfmas();

    #pragma unroll
    for (int mi = 0; mi < 4; ++mi) {
        #pragma unroll
        for (int ni = 0; ni < 4; ++ni) {
            int col = tn + wn + ni * 16 + tr;
            #pragma unroll
            for (int r = 0; r < 4; ++r) {
                int row = tm + wm + mi * 16 + quad * 4 + r;
                size_t o = (size_t)row * N + col;
                float v = acc[mi][ni][r];
                if (ADD) v += C[o];
                C[o] = v;
            }
        }
    }
}

// common swizzle pieces for the 8-phase kernels:
//   slotoff(row,cq) = (row>>1)*128 + ((((row&1)<<2)|cq) ^ ((row>>1)&7))*16
#define BARX() asm volatile("s_barrier" ::: "memory")
#define VMW4() asm volatile("s_waitcnt vmcnt(4)" ::: "memory")
#define VMW3() asm volatile("s_waitcnt vmcnt(3)" ::: "memory")

// ---------------- fused GEMM1, 256x256 tile, 8-phase counted-vmcnt schedule ----------------
#define RD_A(par, ks, MB) { const char* _p = lds + ((par) << 15) + ((ks) << 14); \
    af[0] = *(const bf16x8*)(_p + aoff[(MB)+0]); \
    af[1] = *(const bf16x8*)(_p + aoff[(MB)+1]); \
    af[2] = *(const bf16x8*)(_p + aoff[(MB)+2]); \
    af[3] = *(const bf16x8*)(_p + aoff[(MB)+3]); }

#define RD_B(par, ks) { const char* _p = lds + 65536 + ((par) << 15) + ((ks) << 14); \
    bfv[0] = *(const bf16x8*)(_p + boff[0]); \
    bfv[1] = *(const bf16x8*)(_p + boff[1]); \
    bfv[2] = *(const bf16x8*)(_p + boff[2]); \
    bfv[3] = *(const bf16x8*)(_p + boff[3]); }

#define MMA16(ACC) { __builtin_amdgcn_s_setprio(1); \
    _Pragma("unroll") \
    for (int _i = 0; _i < 4; ++_i) \
        _Pragma("unroll") \
        for (int _n = 0; _n < 4; ++_n) \
            ACC[_i][_n] = __builtin_amdgcn_mfma_f32_16x16x32_bf16(af[_i], bfv[_n], ACC[_i][_n], 0, 0, 0); \
    __builtin_amdgcn_s_setprio(0); }

__global__ __launch_bounds__(512, 2)
void gemm1_8ph(const unsigned short* __restrict__ Xb, const unsigned short* __restrict__ Wg,
               const unsigned short* __restrict__ Wu, unsigned short* __restrict__ Hb) {
    __shared__ __align__(16) char lds[131072];
    const int tid  = threadIdx.x;
    const int lane = tid & 63;
    const int wid  = tid >> 6;
    const int quad = lane >> 4;
    const int tr   = lane & 15;
    const int wm   = (wid >> 2) << 7;   // 0 / 128
    const int wn   = (wid & 3) << 6;    // 0 / 64 / 128 / 192

    const int bid = blockIdx.x;
    const int swz = (bid & 7) * 128 + (bid >> 3);
    const int gm  = (swz & 31) << 8;    // token-row base
    const int gn  = (swz >> 5) << 8;    // Wcat-row base

    const int vsw  = (tid & 7) ^ ((tid >> 3) & 7);
    const int rowb = ((tid >> 3) << 1) | (vsw >> 2);   // 0..127
    const int cq8  = (vsw & 3) << 3;

    const unsigned short* pA0 = Xb + (size_t)(gm + rowb) * HDIM + cq8;
    const unsigned short* pA1 = pA0 + (size_t)128 * HDIM;
    auto wsrc = [&](int R) -> const unsigned short* {
        const unsigned short* base = ((R >> 4) & 1) ? Wu : Wg;
        int sr = ((R >> 5) << 4) | (R & 15);
        return base + (size_t)sr * HDIM + cq8;
    };
    const unsigned short* pB0 = wsrc(gn + rowb);
    const unsigned short* pB1 = wsrc(gn + rowb + 128);

    int aoff[8], boff[4];
    #pragma unroll
    for (int i = 0; i < 8; ++i) {
        int row = wm + i * 16 + tr;
        aoff[i] = ((row >> 1) << 7) | (((((row & 1) << 2) | quad) ^ ((row >> 1) & 7)) << 4);
    }
    #pragma unroll
    for (int i = 0; i < 4; ++i) {
        int row = wn + i * 16 + tr;
        boff[i] = ((row >> 1) << 7) | (((((row & 1) << 2) | quad) ^ ((row >> 1) & 7)) << 4);
    }

    f32x4 accL[4][4] = {};
    f32x4 accH[4][4] = {};
    bf16x8 af[4], bfv[4];

    auto stageA = [&](int nxt, int ks, int kOff) {
        char* d = lds + (nxt << 15) + (ks << 14) + (tid << 4);
        gld_lds16(pA0 + kOff, d);
        gld_lds16(pA1 + kOff, d + 8192);
    };
    auto stageB = [&](int nxt, int ks, int kOff) {
        char* d = lds + 65536 + (nxt << 15) + (ks << 14) + (tid << 4);
        gld_lds16(pB0 + kOff, d);
        gld_lds16(pB1 + kOff, d + 8192);
    };

    stageA(0, 0, 0);  stageB(0, 0, 0);
    stageA(0, 1, 32); stageB(0, 1, 32);
    asm volatile("s_waitcnt vmcnt(0)" ::: "memory");
    BARX();

    for (int t = 0; t < 16; ++t) {
        const int par = t & 1, nxt = par ^ 1;
        const int kN = (t < 15 ? t + 1 : 15) << 6;
        RD_A(par, 0, 0); RD_B(par, 0);
        stageA(nxt, 0, kN);
        BARX();
        MMA16(accL);
        BARX();
        RD_A(par, 0, 4);
        stageB(nxt, 0, kN);
        VMW4(); BARX();
        MMA16(accH);
        BARX();
        RD_A(par, 1, 0); RD_B(par, 1);
        stageA(nxt, 1, kN + 32);
        BARX();
        MMA16(accL);
        BARX();
        RD_A(par, 1, 4);
        stageB(nxt, 1, kN + 32);
        VMW4(); BARX();
        MMA16(accH);
        BARX();
    }
    asm volatile("s_waitcnt vmcnt(0)" ::: "memory");

    const size_t icb = (size_t)((gn + wn) >> 1) + tr;
    const int rbase = gm + wm + quad * 4;
    #pragma unroll
    for (int mi = 0; mi < 4; ++mi) {
        #pragma unroll
        for (int p = 0; p < 2; ++p) {
            #pragma unroll
            for (int r = 0; r < 4; ++r) {
                {
                    float g = accL[mi][2 * p][r], u = accL[mi][2 * p + 1][r];
                    float h = g / (1.0f + __expf(-g)) * u;
                    Hb[(size_t)(rbase + mi * 16 + r) * IDIM + icb + 16 * p] = f2bf(h);
                }
                {
                    float g = accH[mi][2 * p][r], u = accH[mi][2 * p + 1][r];
                    float h = g / (1.0f + __expf(-g)) * u;
                    Hb[(size_t)(rbase + 64 + mi * 16 + r) * IDIM + icb + 16 * p] = f2bf(h);
                }
            }
        }
    }
}

// ---------------- GEMM2 (down-proj): out += hbuf @ downb^T, 256x128 tile, counted-vmcnt ----------------
// A = hbuf [8192, 4096], B = downb [1024, 4096], C = out [8192, 1024] fp32 accumulate.
// BK=64, 2 phases/K-tile (ks halves), 16 MFMA/phase, vmcnt(3) per phase (3 stages/thread/phase).
// LDS 96KB: A 4 x 16KB slots @0, B 4 x 8KB slots @65536. Same XOR row-pair swizzle as gemm1.
#define RD2_A(par, ks) { const char* _p = lds + ((par) << 15) + ((ks) << 14); \
    _Pragma("unroll") \
    for (int _i = 0; _i < 8; ++_i) af[_i] = *(const bf16x8*)(_p + aoff[_i]); }

#define RD2_B(par, ks) { const char* _p = lds + 65536 + ((par) << 14) + ((ks) << 13); \
    bfv[0] = *(const bf16x8*)(_p + boff[0]); \
    bfv[1] = *(const bf16x8*)(_p + boff[1]); }

#define MMA2() { __builtin_amdgcn_s_setprio(1); \
    _Pragma("unroll") \
    for (int _i = 0; _i < 8; ++_i) \
        _Pragma("unroll") \
        for (int _n = 0; _n < 2; ++_n) \
            acc[_i][_n] = __builtin_amdgcn_mfma_f32_16x16x32_bf16(af[_i], bfv[_n], acc[_i][_n], 0, 0, 0); \
    __builtin_amdgcn_s_setprio(0); }

__global__ __launch_bounds__(512, 2)
void gemm2_8ph(const unsigned short* __restrict__ A, const unsigned short* __restrict__ B,
               float* __restrict__ C) {
    __shared__ __align__(16) char lds[98304];
    const int K = IDIM, N = HDIM;
    const int tid  = threadIdx.x;
    const int lane = tid & 63;
    const int wid  = tid >> 6;
    const int quad = lane >> 4;
    const int tr   = lane & 15;
    const int wm   = (wid >> 2) << 7;   // 0 / 128
    const int wn   = (wid & 3) << 5;    // 0 / 32 / 64 / 96

    // 256 blocks, 8 XCDs -> 32 contiguous per XCD; each XCD owns one 128-col B stripe (1MB, L2-hot)
    const int bid = blockIdx.x;
    const int swz = (bid & 7) * 32 + (bid >> 3);
    const int gm  = (swz & 31) << 8;    // 0..7936
    const int gn  = (swz >> 5) << 7;    // 0..896

    const int vsw  = (tid & 7) ^ ((tid >> 3) & 7);
    const int rowb = ((tid >> 3) << 1) | (vsw >> 2);   // 0..127
    const int cq8  = (vsw & 3) << 3;

    const unsigned short* pA0 = A + (size_t)(gm + rowb) * K + cq8;
    const unsigned short* pA1 = pA0 + (size_t)128 * K;
    const unsigned short* pB0 = B + (size_t)(gn + rowb) * K + cq8;

    int aoff[8], boff[2];
    #pragma unroll
    for (int i = 0; i < 8; ++i) {
        int row = wm + i * 16 + tr;
        aoff[i] = ((row >> 1) << 7) | (((((row & 1) << 2) | quad) ^ ((row >> 1) & 7)) << 4);
    }
    #pragma unroll
    for (int i = 0; i < 2; ++i) {
        int row = wn + i * 16 + tr;
        boff[i] = ((row >> 1) << 7) | (((((row & 1) << 2) | quad) ^ ((row >> 1) & 7)) << 4);
    }

    f32x4 acc[8][2] = {};
    bf16x8 af[8], bfv[2];

    auto stageA = [&](int nxt, int ks, int kOff) {
        char* d = lds + (nxt << 15) + (ks << 14) + (tid << 4);
        gld_lds16(pA0 + kOff, d);
        gld_lds16(pA1 + kOff, d + 8192);
    };
    auto stageB = [&](int nxt, int ks, int kOff) {
        char* d = lds + 65536 + (nxt << 14) + (ks << 13) + (tid << 4);
        gld_lds16(pB0 + kOff, d);
    };

    // prologue: stage K-tile 0 fully
    stageA(0, 0, 0); stageB(0, 0, 0);
    stageA(0, 1, 32); stageB(0, 1, 32);
    asm volatile("s_waitcnt vmcnt(0)" ::: "memory");
    BARX();

    for (int t = 0; t < 64; ++t) {
        const int par = t & 1, nxt = par ^ 1;
        const int kN = (t < 63 ? t + 1 : 63) << 6;
        // P0: ks0
        RD2_A(par, 0); RD2_B(par, 0);
        stageA(nxt, 0, kN); stageB(nxt, 0, kN);
        VMW3(); BARX();
        MMA2();
        BARX();
        // P1: ks1
        RD2_A(par, 1); RD2_B(par, 1);
        stageA(nxt, 1, kN + 32); stageB(nxt, 1, kN + 32);
        VMW3(); BARX();
        MMA2();
        BARX();
    }
    asm volatile("s_waitcnt vmcnt(0)" ::: "memory");

    // epilogue: C += acc
    #pragma unroll
    for (int mi = 0; mi < 8; ++mi) {
        #pragma unroll
        for (int ni = 0; ni < 2; ++ni) {
            int col = gn + wn + ni * 16 + tr;
            #pragma unroll
            for (int r = 0; r < 4; ++r) {
                int row = gm + wm + mi * 16 + quad * 4 + r;
                size_t o = (size_t)row * N + col;
                C[o] += acc[mi][ni][r];
            }
        }
    }
}

// ---------------- batchnorm stats ----------------
__global__ void bn_stats(const float* __restrict__ gxy, float* __restrict__ sums, float* __restrict__ ssq) {
    const int j = threadIdx.x;
    const int b = blockIdx.x;
    float s = 0.f, q = 0.f;
    for (int r = 0; r < 32; ++r) {
        float v = gxy[(size_t)(b * 32 + r) * 256 + j];
        s += v; q += v * v;
    }
    atomicAdd(&sums[j], s);
    atomicAdd(&ssq[j], q);
}

// ---------------- routing: bn -> log_softmax -> top16 via candidate reduction ----------------
__global__ __launch_bounds__(256)
void routing_kernel(const float* __restrict__ gxy, const float* __restrict__ sums,
                    const float* __restrict__ ssq, int* __restrict__ oidx, float* __restrict__ owt) {
    const int lane = threadIdx.x & 63;
    const int t = blockIdx.x * 4 + (threadIdx.x >> 6);
    const float invT = 1.0f / (float)T_TOK;
    const float* g = gxy + (size_t)t * 256;

    float z[4];
    const int cols[4] = {lane, lane + 64, 128 + lane, 192 + lane};
    #pragma unroll
    for (int i = 0; i < 4; ++i) {
        int c = cols[i];
        float mu  = sums[c] * invT;
        float var = ssq[c] * invT - mu * mu;
        z[i] = (g[c] - mu) * rsqrtf(var + 1e-5f);
    }
    float mx = fmaxf(z[0], z[1]);
    float my = fmaxf(z[2], z[3]);
    #pragma unroll
    for (int m = 32; m >= 1; m >>= 1) {
        mx = fmaxf(mx, __shfl_xor(mx, m));
        my = fmaxf(my, __shfl_xor(my, m));
    }
    float sx = __expf(z[0] - mx) + __expf(z[1] - mx);
    float sy = __expf(z[2] - my) + __expf(z[3] - my);
    #pragma unroll
    for (int m = 32; m >= 1; m >>= 1) {
        sx += __shfl_xor(sx, m);
        sy += __shfl_xor(sy, m);
    }
    float lx0 = z[0] - (mx + __logf(sx)), lx1 = z[1] - (mx + __logf(sx));
    float ly0 = z[2] - (my + __logf(sy)), ly1 = z[3] - (my + __logf(sy));

    float aw = -INFINITY; int ai = 0;
    float bw = -INFINITY; int bi = 0;
    {
        float v0 = lx0, v1 = lx1;
        for (int i = 0; i < 16; ++i) {
            float v; int c;
            if (v0 >= v1) { v = v0; c = lane; } else { v = v1; c = lane + 64; }
            #pragma unroll
            for (int m = 32; m >= 1; m >>= 1) {
                float ov = __shfl_xor(v, m); int oc = __shfl_xor(c, m);
                if (ov > v || (ov == v && oc < c)) { v = ov; c = oc; }
            }
            if ((c & 63) == lane) { if (c < 64) v0 = -INFINITY; else v1 = -INFINITY; }
            if (lane == i) { aw = v; ai = c; }
        }
    }
    {
        float v0 = ly0, v1 = ly1;
        for (int i = 0; i < 16; ++i) {
            float v; int c;
            if (v0 >= v1) { v = v0; c = lane; } else { v = v1; c = lane + 64; }
            #pragma unroll
            for (int m = 32; m >= 1; m >>= 1) {
                float ov = __shfl_xor(v, m); int oc = __shfl_xor(c, m);
                if (ov > v || (ov == v && oc < c)) { v = ov; c = oc; }
            }
            if ((c & 63) == lane) { if (c < 64) v0 = -INFINITY; else v1 = -INFINITY; }
            if (lane == i) { bw = v; bi = c; }
        }
    }
    float cv[4];
    #pragma unroll
    for (int j = 0; j < 4; ++j) {
        int c = lane + 64 * j;
        cv[j] = __shfl(aw, c >> 4) + __shfl(bw, c & 15);
    }
    int myidx = 0; float myw = 0.f;
    for (int i = 0; i < 16; ++i) {
        float v = cv[0]; int c = lane;
        #pragma unroll
        for (int j = 1; j < 4; ++j) { int cc = lane + 64 * j; if (cv[j] > v) { v = cv[j]; c = cc; } }
        #pragma unroll
        for (int m = 32; m >= 1; m >>= 1) {
            float ov = __shfl_xor(v, m); int oc = __shfl_xor(c, m);
            if (ov > v || (ov == v && oc < c)) { v = ov; c = oc; }
        }
        #pragma unroll
        for (int j = 0; j < 4; ++j) if (c == lane + 64 * j) cv[j] = -INFINITY;
        int p = c >> 4, q = c & 15;
        int ex = __shfl(ai, p);
        int ey = __shfl(bi, q);
        if (lane == i) { myidx = ex * 128 + ey; myw = __expf(v); }
    }
    if (lane < 16) {
        oidx[t * TOPK + lane] = myidx;
        owt[t * TOPK + lane]  = myw;
    }
}

// ---------------- expert gather/combine (bf16 tables + bf16 x) ----------------
__global__ __launch_bounds__(256)
void expert_combine(const unsigned short* __restrict__ xb, const int* __restrict__ idx,
                    const float* __restrict__ wts, const unsigned short* __restrict__ ueb,
                    const unsigned short* __restrict__ deb, float* __restrict__ out) {
    const int t = blockIdx.x;
    const int tid = threadIdx.x;
    const int lane = tid & 63, wv = tid >> 6;
    __shared__ float part[TOPK * 4];
    __shared__ float sc[TOPK];
    ushort4 xv4 = ((const ushort4*)(xb + (size_t)t * HDIM))[tid];
    float x0 = bf2f(xv4.x), x1 = bf2f(xv4.y), x2 = bf2f(xv4.z), x3 = bf2f(xv4.w);
    int e[TOPK];
    #pragma unroll
    for (int k = 0; k < TOPK; ++k) e[k] = idx[t * TOPK + k];
    #pragma unroll
    for (int k = 0; k < TOPK; ++k) {
        ushort4 u4 = ((const ushort4*)(ueb + (size_t)e[k] * HDIM))[tid];
        float p = bf2f(u4.x) * x0 + bf2f(u4.y) * x1 + bf2f(u4.z) * x2 + bf2f(u4.w) * x3;
        #pragma unroll
        for (int m = 32; m >= 1; m >>= 1) p += __shfl_xor(p, m);
        if (lane == 0) part[k * 4 + wv] = p;
    }
    __syncthreads();
    if (tid < TOPK) {
        float s = part[tid * 4] + part[tid * 4 + 1] + part[tid * 4 + 2] + part[tid * 4 + 3];
        sc[tid] = s * wts[t * TOPK + tid];
    }
    __syncthreads();
    float4 acc = {0.f, 0.f, 0.f, 0.f};
    #pragma unroll
    for (int k = 0; k < TOPK; ++k) {
        float s = sc[k];
        ushort4 d4 = ((const ushort4*)(deb + (size_t)e[k] * HDIM))[tid];
        acc.x += s * bf2f(d4.x); acc.y += s * bf2f(d4.y);
        acc.z += s * bf2f(d4.z); acc.w += s * bf2f(d4.w);
    }
    ((float4*)(out + (size_t)t * HDIM))[tid] = acc;
}

extern "C" void kernel_launch(void* const* d_in, const int* in_sizes, int n_in,
                              void* d_out, int out_size, void* d_ws, size_t ws_size,
                              hipStream_t stream) {
    const float* x  = (const float*)d_in[0];
    const float* gw = (const float*)d_in[1];
    const float* uw = (const float*)d_in[2];
    const float* dw = (const float*)d_in[3];
    const float* wx = (const float*)d_in[4];
    const float* wy = (const float*)d_in[5];
    const float* ue = (const float*)d_in[6];
    const float* de = (const float*)d_in[7];
    float* out = (float*)d_out;

    char* ws = (char*)d_ws;
    size_t o = 0;
    auto alloc = [&](size_t bytes) { void* p = ws + o; o += (bytes + 255) & ~(size_t)255; return p; };
    unsigned short* xb    = (unsigned short*)alloc((size_t)T_TOK * HDIM * 2);
    unsigned short* gateb = (unsigned short*)alloc((size_t)IDIM * HDIM * 2);
    unsigned short* upb   = (unsigned short*)alloc((size_t)IDIM * HDIM * 2);
    unsigned short* downb = (unsigned short*)alloc((size_t)HDIM * IDIM * 2);
    unsigned short* wrb   = (unsigned short*)alloc((size_t)256 * HDIM * 2);
    unsigned short* ueb   = (unsigned short*)alloc((size_t)16384 * HDIM * 2);
    unsigned short* deb   = (unsigned short*)alloc((size_t)16384 * HDIM * 2);
    unsigned short* hbuf  = (unsigned short*)alloc((size_t)T_TOK * IDIM * 2);
    float* gxy  = (float*)alloc((size_t)T_TOK * 256 * 4);
    float* sums = (float*)alloc(256 * 4);
    float* ssq  = (float*)alloc(256 * 4);
    int*   idxs = (int*)alloc((size_t)T_TOK * TOPK * 4);
    float* wts  = (float*)alloc((size_t)T_TOK * TOPK * 4);

    // merged converts (8 segments)
    CvtSegs segs;
    const float* srcs[8] = {x, gw, uw, dw, wx, wy, ue, de};
    unsigned short* dsts[8] = {xb, gateb, upb, downb, wrb, wrb + SDIM * HDIM, ueb, deb};
    const int cnt4[8] = {T_TOK * HDIM / 4, IDIM * HDIM / 4, IDIM * HDIM / 4, IDIM * HDIM / 4,
                         SDIM * HDIM / 4, SDIM * HDIM / 4, 16384 * HDIM / 4, 16384 * HDIM / 4};
    int acc = 0;
    for (int i = 0; i < 8; ++i) {
        segs.src[i] = (const float4*)srcs[i];
        segs.dst[i] = (ushort4*)dsts[i];
        acc += cnt4[i];
        segs.end[i] = acc;
    }
    cvt_all_kernel<<<(acc + 255) / 256, 256, 0, stream>>>(segs);

    // router logits: gxy[T,256] = xb @ wrb^T
    hipMemsetAsync(sums, 0, 2 * 256 * 4, stream);  // sums+ssq contiguous
    gemm_bt<0><<<dim3(T_TOK / 128, 256 / 128), 256, 0, stream>>>(xb, wrb, gxy, T_TOK, 256, HDIM);
    bn_stats<<<256, 256, 0, stream>>>(gxy, sums, ssq);
    routing_kernel<<<T_TOK / 4, 256, 0, stream>>>(gxy, sums, ssq, idxs, wts);

    // expert branch writes out fully
    expert_combine<<<T_TOK, 256, 0, stream>>>(xb, idxs, wts, ueb, deb, out);

    // MLP branch: fused gate/up 8-phase GEMM, then 8-phase down-proj accumulate
    gemm1_8ph<<<1024, 512, 0, stream>>>(xb, gateb, upb, hbuf);
    gemm2_8ph<<<256, 512, 0, stream>>>(hbuf, downb, out);
}

// Round 4
// 634.807 us; speedup vs baseline: 1.3524x; 1.0876x over previous
//
#include <hip/hip_runtime.h>
#include <hip/hip_bf16.h>
#include <math.h>

#define T_TOK 8192
#define HDIM  1024
#define IDIM  4096
#define SDIM  128
#define TOPK  16

typedef __bf16 bf16x8 __attribute__((ext_vector_type(8)));
typedef float  f32x4  __attribute__((ext_vector_type(4)));

__device__ __forceinline__ unsigned short f2bf(float f) {
    union { float f; unsigned u; } a; a.f = f;
    unsigned r = a.u + 0x7fffu + ((a.u >> 16) & 1u);
    return (unsigned short)(r >> 16);
}
__device__ __forceinline__ float bf2f(unsigned short b) {
    union { unsigned u; float f; } a; a.u = ((unsigned)b) << 16;
    return a.f;
}

__device__ __forceinline__ void gld_lds16(const void* g, void* l) {
    __builtin_amdgcn_global_load_lds(
        (__attribute__((address_space(1))) void*)g,
        (__attribute__((address_space(3))) void*)l,
        16, 0, 0);
}

// ---------------- merged fp32 -> bf16 convert over 8 segments ----------------
struct CvtSegs {
    const float4* src[8];
    ushort4*      dst[8];
    int           end[8];   // prefix-sum of float4 counts
};

__global__ __launch_bounds__(256)
void cvt_all_kernel(CvtSegs segs) {
    int i = blockIdx.x * 256 + threadIdx.x;
    if (i >= segs.end[7]) return;
    int s = 0;
    #pragma unroll
    for (int k = 0; k < 7; ++k) s += (i >= segs.end[k]) ? 1 : 0;
    int base = (s == 0) ? 0 : segs.end[s - 1];
    int j = i - base;
    float4 v = segs.src[s][j];
    ushort4 o;
    o.x = f2bf(v.x); o.y = f2bf(v.y); o.z = f2bf(v.z); o.w = f2bf(v.w);
    segs.dst[s][j] = o;
}

// ---------------- generic C = A * B^T (bf16 in, fp32 out), 128x128 tile ----------------
// (kept only for the small router GEMM)
template<int ADD>
__global__ __launch_bounds__(256)
void gemm_bt(const unsigned short* __restrict__ A, const unsigned short* __restrict__ B,
             float* __restrict__ C, int M, int N, int K) {
    __shared__ unsigned short As[4096];  // [kc=4][m=128][8] bf16
    __shared__ unsigned short Bs[4096];  // [kc=4][n=128][8]
    const int tid  = threadIdx.x;
    const int lane = tid & 63;
    const int wave = tid >> 6;
    const int tm = blockIdx.x * 128;
    const int tn = blockIdx.y * 128;
    const int wm = (wave & 1) * 64;
    const int wn = (wave >> 1) * 64;
    const int quad = lane >> 4;
    const int tr   = lane & 15;

    f32x4 acc[4][4] = {};
    bf16x8 af[4], bfr[4];

    const int ua0 = tid,        am0 = ua0 & 127, ak0 = ua0 >> 7;
    const int ua1 = tid + 256,  am1 = ua1 & 127, ak1 = ua1 >> 7;

    auto issue = [&](int kt) {
        gld_lds16(A + (size_t)(tm + am0) * K + kt + ak0 * 8, &As[ua0 * 8]);
        gld_lds16(A + (size_t)(tm + am1) * K + kt + ak1 * 8, &As[ua1 * 8]);
        gld_lds16(B + (size_t)(tn + am0) * K + kt + ak0 * 8, &Bs[ua0 * 8]);
        gld_lds16(B + (size_t)(tn + am1) * K + kt + ak1 * 8, &Bs[ua1 * 8]);
    };
    auto rdfrags = [&]() {
        #pragma unroll
        for (int mi = 0; mi < 4; ++mi)
            af[mi] = *(const bf16x8*)&As[(quad * 128 + wm + mi * 16 + tr) * 8];
        #pragma unroll
        for (int ni = 0; ni < 4; ++ni)
            bfr[ni] = *(const bf16x8*)&Bs[(quad * 128 + wn + ni * 16 + tr) * 8];
    };
    auto mfmas = [&]() {
        #pragma unroll
        for (int mi = 0; mi < 4; ++mi)
            #pragma unroll
            for (int ni = 0; ni < 4; ++ni)
                acc[mi][ni] = __builtin_amdgcn_mfma_f32_16x16x32_bf16(af[mi], bfr[ni], acc[mi][ni], 0, 0, 0);
    };

    issue(0);
    asm volatile("s_waitcnt vmcnt(0)" ::: "memory");
    __syncthreads();
    rdfrags();
    for (int kt = 32; kt < K; kt += 32) {
        __syncthreads();
        issue(kt);
        mfmas();
        asm volatile("s_waitcnt vmcnt(0)" ::: "memory");
        __syncthreads();
        rdfrags();
    }
    mfmas();

    #pragma unroll
    for (int mi = 0; mi < 4; ++mi) {
        #pragma unroll
        for (int ni = 0; ni < 4; ++ni) {
            int col = tn + wn + ni * 16 + tr;
            #pragma unroll
            for (int r = 0; r < 4; ++r) {
                int row = tm + wm + mi * 16 + quad * 4 + r;
                size_t o = (size_t)row * N + col;
                float v = acc[mi][ni][r];
                if (ADD) v += C[o];
                C[o] = v;
            }
        }
    }
}

// common swizzle pieces for the ring kernels:
//   slotoff(row,cq) = (row>>1)*128 + ((((row&1)<<2)|cq) ^ ((row>>1)&7))*16
#define BARX() asm volatile("s_barrier" ::: "memory")
#define VMW(n) asm volatile("s_waitcnt vmcnt(" #n ")" ::: "memory")

// ---------------- fused GEMM1, 256x256 tile, BK=32 ring-4 counted-vmcnt schedule ----------------
// h = silu(x @ Wg^T) * (x @ Wu^T), bf16 out. Virtual interleaved Wcat as before.
// Ring: 4 slots per operand (slot = 256 rows x 32 cols bf16 = 16KB). Tile t+3 staged during
// tile t (A at P0, B at P1); enforced by vmcnt(8) at following tiles' P1 -> ~5.5 phase budget.
// XCD map: each XCD owns 4 gm (2MB A, L2-resident) x all 32 gn (B streams).
#define RD_A(r, MB) { const char* _p = lds + ((r) << 14); \
    af[0] = *(const bf16x8*)(_p + aoff[(MB)+0]); \
    af[1] = *(const bf16x8*)(_p + aoff[(MB)+1]); \
    af[2] = *(const bf16x8*)(_p + aoff[(MB)+2]); \
    af[3] = *(const bf16x8*)(_p + aoff[(MB)+3]); }

#define RD_B(r) { const char* _p = lds + 65536 + ((r) << 14); \
    bfv[0] = *(const bf16x8*)(_p + boff[0]); \
    bfv[1] = *(const bf16x8*)(_p + boff[1]); \
    bfv[2] = *(const bf16x8*)(_p + boff[2]); \
    bfv[3] = *(const bf16x8*)(_p + boff[3]); }

#define MMA16(ACC) { __builtin_amdgcn_s_setprio(1); \
    _Pragma("unroll") \
    for (int _i = 0; _i < 4; ++_i) \
        _Pragma("unroll") \
        for (int _n = 0; _n < 4; ++_n) \
            ACC[_i][_n] = __builtin_amdgcn_mfma_f32_16x16x32_bf16(af[_i], bfv[_n], ACC[_i][_n], 0, 0, 0); \
    __builtin_amdgcn_s_setprio(0); }

__global__ __launch_bounds__(512, 2)
void gemm1_8ph(const unsigned short* __restrict__ Xb, const unsigned short* __restrict__ Wg,
               const unsigned short* __restrict__ Wu, unsigned short* __restrict__ Hb) {
    __shared__ __align__(16) char lds[131072];
    const int tid  = threadIdx.x;
    const int lane = tid & 63;
    const int wid  = tid >> 6;
    const int quad = lane >> 4;
    const int tr   = lane & 15;
    const int wm   = (wid >> 2) << 7;   // 0 / 128
    const int wn   = (wid & 3) << 6;    // 0 / 64 / 128 / 192

    // XCD map: xcd = bid&7 owns gm in {xcd*4 .. xcd*4+3} (A 2MB, L2-resident), gn sweeps 0..31.
    const int bid = blockIdx.x;
    const int u   = bid >> 3;
    const int gm  = (((bid & 7) << 2) | (u & 3)) << 8;
    const int gn  = (u >> 2) << 8;

    // staging thread map (inverse of the LDS swizzle, so gld_lds dest stays linear)
    const int vsw  = (tid & 7) ^ ((tid >> 3) & 7);
    const int rowb = ((tid >> 3) << 1) | (vsw >> 2);   // 0..127
    const int cq8  = (vsw & 3) << 3;

    const unsigned short* pA0 = Xb + (size_t)(gm + rowb) * HDIM + cq8;
    const unsigned short* pA1 = pA0 + (size_t)128 * HDIM;
    auto wsrc = [&](int R) -> const unsigned short* {
        const unsigned short* base = ((R >> 4) & 1) ? Wu : Wg;
        int sr = ((R >> 5) << 4) | (R & 15);
        return base + (size_t)sr * HDIM + cq8;
    };
    const unsigned short* pB0 = wsrc(gn + rowb);
    const unsigned short* pB1 = wsrc(gn + rowb + 128);

    int aoff[8], boff[4];
    #pragma unroll
    for (int i = 0; i < 8; ++i) {
        int row = wm + i * 16 + tr;
        aoff[i] = ((row >> 1) << 7) | (((((row & 1) << 2) | quad) ^ ((row >> 1) & 7)) << 4);
    }
    #pragma unroll
    for (int i = 0; i < 4; ++i) {
        int row = wn + i * 16 + tr;
        boff[i] = ((row >> 1) << 7) | (((((row & 1) << 2) | quad) ^ ((row >> 1) & 7)) << 4);
    }

    f32x4 accL[4][4] = {};
    f32x4 accH[4][4] = {};
    bf16x8 af[4], bfv[4];

    auto stageA = [&](int slot, int kOff) {
        char* d = lds + (slot << 14) + (tid << 4);
        gld_lds16(pA0 + kOff, d);
        gld_lds16(pA1 + kOff, d + 8192);
    };
    auto stageB = [&](int slot, int kOff) {
        char* d = lds + 65536 + (slot << 14) + (tid << 4);
        gld_lds16(pB0 + kOff, d);
        gld_lds16(pB1 + kOff, d + 8192);
    };

    // prologue: stage tiles 0,1,2 (12 loads); vmcnt(8) -> tile0 complete
    stageA(0, 0);  stageB(0, 0);
    stageA(1, 32); stageB(1, 32);
    stageA(2, 64); stageB(2, 64);
    VMW(8); BARX();

    for (int t = 0; t < 32; ++t) {
        const int r  = t & 3;
        const int rn = (t + 3) & 3;
        const int kN = (t < 29 ? t + 3 : 31) << 5;   // clamped (dummy restage, never read)
        // P0: mi 0-3
        RD_A(r, 0); RD_B(r);
        stageA(rn, kN);
        BARX();
        MMA16(accL);
        BARX();
        // P1: mi 4-7
        RD_A(r, 4);
        stageB(rn, kN);
        VMW(8); BARX();
        MMA16(accH);
        BARX();
    }
    asm volatile("s_waitcnt vmcnt(0)" ::: "memory");  // drain DMA before block retires

    const size_t icb = (size_t)((gn + wn) >> 1) + tr;
    const int rbase = gm + wm + quad * 4;
    #pragma unroll
    for (int mi = 0; mi < 4; ++mi) {
        #pragma unroll
        for (int p = 0; p < 2; ++p) {
            #pragma unroll
            for (int r = 0; r < 4; ++r) {
                {
                    float g = accL[mi][2 * p][r], u2 = accL[mi][2 * p + 1][r];
                    float h = g / (1.0f + __expf(-g)) * u2;
                    Hb[(size_t)(rbase + mi * 16 + r) * IDIM + icb + 16 * p] = f2bf(h);
                }
                {
                    float g = accH[mi][2 * p][r], u2 = accH[mi][2 * p + 1][r];
                    float h = g / (1.0f + __expf(-g)) * u2;
                    Hb[(size_t)(rbase + 64 + mi * 16 + r) * IDIM + icb + 16 * p] = f2bf(h);
                }
            }
        }
    }
}

// ---------------- GEMM2 (down-proj): out += hbuf @ downb^T, 256x128 tile, BK=32 ring-4 ----------------
// A slot 256x32 = 16KB (4 slots @0), B slot 128x32 = 8KB (4 slots @65536); 96KB total.
// Tile t+3 staged during tile t (3 loads/thread); vmcnt(6) per tile retires tile t+1's loads.
// XCD map: each XCD owns 4 gm x 8 gn (16MB working set vs 65MB before).
#define RD2_A(r) { const char* _p = lds + ((r) << 14); \
    _Pragma("unroll") \
    for (int _i = 0; _i < 8; ++_i) af[_i] = *(const bf16x8*)(_p + aoff[_i]); }

#define RD2_B(r) { const char* _p = lds + 65536 + ((r) << 13); \
    bfv[0] = *(const bf16x8*)(_p + boff[0]); \
    bfv[1] = *(const bf16x8*)(_p + boff[1]); }

#define MMA2() { __builtin_amdgcn_s_setprio(1); \
    _Pragma("unroll") \
    for (int _i = 0; _i < 8; ++_i) \
        _Pragma("unroll") \
        for (int _n = 0; _n < 2; ++_n) \
            acc[_i][_n] = __builtin_amdgcn_mfma_f32_16x16x32_bf16(af[_i], bfv[_n], acc[_i][_n], 0, 0, 0); \
    __builtin_amdgcn_s_setprio(0); }

__global__ __launch_bounds__(512, 2)
void gemm2_8ph(const unsigned short* __restrict__ A, const unsigned short* __restrict__ B,
               float* __restrict__ C) {
    __shared__ __align__(16) char lds[98304];
    const int K = IDIM, N = HDIM;
    const int tid  = threadIdx.x;
    const int lane = tid & 63;
    const int wid  = tid >> 6;
    const int quad = lane >> 4;
    const int tr   = lane & 15;
    const int wm   = (wid >> 2) << 7;   // 0 / 128
    const int wn   = (wid & 3) << 5;    // 0 / 32 / 64 / 96

    // XCD map: xcd = bid&7 owns gm in {xcd*4..xcd*4+3} x gn 0..7 (A 8MB + B 8MB per XCD)
    const int bid = blockIdx.x;
    const int u   = bid >> 3;
    const int gm  = (((bid & 7) << 2) | (u >> 3)) << 8;   // 0..7936
    const int gn  = (u & 7) << 7;                          // 0..896

    const int vsw  = (tid & 7) ^ ((tid >> 3) & 7);
    const int rowb = ((tid >> 3) << 1) | (vsw >> 2);   // 0..127
    const int cq8  = (vsw & 3) << 3;

    const unsigned short* pA0 = A + (size_t)(gm + rowb) * K + cq8;
    const unsigned short* pA1 = pA0 + (size_t)128 * K;
    const unsigned short* pB0 = B + (size_t)(gn + rowb) * K + cq8;

    int aoff[8], boff[2];
    #pragma unroll
    for (int i = 0; i < 8; ++i) {
        int row = wm + i * 16 + tr;
        aoff[i] = ((row >> 1) << 7) | (((((row & 1) << 2) | quad) ^ ((row >> 1) & 7)) << 4);
    }
    #pragma unroll
    for (int i = 0; i < 2; ++i) {
        int row = wn + i * 16 + tr;
        boff[i] = ((row >> 1) << 7) | (((((row & 1) << 2) | quad) ^ ((row >> 1) & 7)) << 4);
    }

    f32x4 acc[8][2] = {};
    bf16x8 af[8], bfv[2];

    auto stageA = [&](int slot, int kOff) {
        char* d = lds + (slot << 14) + (tid << 4);
        gld_lds16(pA0 + kOff, d);
        gld_lds16(pA1 + kOff, d + 8192);
    };
    auto stageB = [&](int slot, int kOff) {
        char* d = lds + 65536 + (slot << 13) + (tid << 4);
        gld_lds16(pB0 + kOff, d);
    };

    // prologue: stage tiles 0,1,2 (9 loads); vmcnt(6) -> tile0 complete
    stageA(0, 0);  stageB(0, 0);
    stageA(1, 32); stageB(1, 32);
    stageA(2, 64); stageB(2, 64);
    VMW(6); BARX();

    for (int t = 0; t < 128; ++t) {
        const int r  = t & 3;
        const int rn = (t + 3) & 3;
        const int kN = (t < 125 ? t + 3 : 127) << 5;
        RD2_A(r); RD2_B(r);
        stageA(rn, kN); stageB(rn, kN);
        VMW(6); BARX();
        MMA2();
        BARX();
    }
    asm volatile("s_waitcnt vmcnt(0)" ::: "memory");

    // epilogue: C += acc
    #pragma unroll
    for (int mi = 0; mi < 8; ++mi) {
        #pragma unroll
        for (int ni = 0; ni < 2; ++ni) {
            int col = gn + wn + ni * 16 + tr;
            #pragma unroll
            for (int r = 0; r < 4; ++r) {
                int row = gm + wm + mi * 16 + quad * 4 + r;
                size_t o = (size_t)row * N + col;
                C[o] += acc[mi][ni][r];
            }
        }
    }
}

// ---------------- batchnorm stats ----------------
__global__ void bn_stats(const float* __restrict__ gxy, float* __restrict__ sums, float* __restrict__ ssq) {
    const int j = threadIdx.x;
    const int b = blockIdx.x;
    float s = 0.f, q = 0.f;
    for (int r = 0; r < 32; ++r) {
        float v = gxy[(size_t)(b * 32 + r) * 256 + j];
        s += v; q += v * v;
    }
    atomicAdd(&sums[j], s);
    atomicAdd(&ssq[j], q);
}

// ---------------- routing: bn -> log_softmax -> top16 via candidate reduction ----------------
__global__ __launch_bounds__(256)
void routing_kernel(const float* __restrict__ gxy, const float* __restrict__ sums,
                    const float* __restrict__ ssq, int* __restrict__ oidx, float* __restrict__ owt) {
    const int lane = threadIdx.x & 63;
    const int t = blockIdx.x * 4 + (threadIdx.x >> 6);
    const float invT = 1.0f / (float)T_TOK;
    const float* g = gxy + (size_t)t * 256;

    float z[4];
    const int cols[4] = {lane, lane + 64, 128 + lane, 192 + lane};
    #pragma unroll
    for (int i = 0; i < 4; ++i) {
        int c = cols[i];
        float mu  = sums[c] * invT;
        float var = ssq[c] * invT - mu * mu;
        z[i] = (g[c] - mu) * rsqrtf(var + 1e-5f);
    }
    float mx = fmaxf(z[0], z[1]);
    float my = fmaxf(z[2], z[3]);
    #pragma unroll
    for (int m = 32; m >= 1; m >>= 1) {
        mx = fmaxf(mx, __shfl_xor(mx, m));
        my = fmaxf(my, __shfl_xor(my, m));
    }
    float sx = __expf(z[0] - mx) + __expf(z[1] - mx);
    float sy = __expf(z[2] - my) + __expf(z[3] - my);
    #pragma unroll
    for (int m = 32; m >= 1; m >>= 1) {
        sx += __shfl_xor(sx, m);
        sy += __shfl_xor(sy, m);
    }
    float lx0 = z[0] - (mx + __logf(sx)), lx1 = z[1] - (mx + __logf(sx));
    float ly0 = z[2] - (my + __logf(sy)), ly1 = z[3] - (my + __logf(sy));

    float aw = -INFINITY; int ai = 0;
    float bw = -INFINITY; int bi = 0;
    {
        float v0 = lx0, v1 = lx1;
        for (int i = 0; i < 16; ++i) {
            float v; int c;
            if (v0 >= v1) { v = v0; c = lane; } else { v = v1; c = lane + 64; }
            #pragma unroll
            for (int m = 32; m >= 1; m >>= 1) {
                float ov = __shfl_xor(v, m); int oc = __shfl_xor(c, m);
                if (ov > v || (ov == v && oc < c)) { v = ov; c = oc; }
            }
            if ((c & 63) == lane) { if (c < 64) v0 = -INFINITY; else v1 = -INFINITY; }
            if (lane == i) { aw = v; ai = c; }
        }
    }
    {
        float v0 = ly0, v1 = ly1;
        for (int i = 0; i < 16; ++i) {
            float v; int c;
            if (v0 >= v1) { v = v0; c = lane; } else { v = v1; c = lane + 64; }
            #pragma unroll
            for (int m = 32; m >= 1; m >>= 1) {
                float ov = __shfl_xor(v, m); int oc = __shfl_xor(c, m);
                if (ov > v || (ov == v && oc < c)) { v = ov; c = oc; }
            }
            if ((c & 63) == lane) { if (c < 64) v0 = -INFINITY; else v1 = -INFINITY; }
            if (lane == i) { bw = v; bi = c; }
        }
    }
    float cv[4];
    #pragma unroll
    for (int j = 0; j < 4; ++j) {
        int c = lane + 64 * j;
        cv[j] = __shfl(aw, c >> 4) + __shfl(bw, c & 15);
    }
    int myidx = 0; float myw = 0.f;
    for (int i = 0; i < 16; ++i) {
        float v = cv[0]; int c = lane;
        #pragma unroll
        for (int j = 1; j < 4; ++j) { int cc = lane + 64 * j; if (cv[j] > v) { v = cv[j]; c = cc; } }
        #pragma unroll
        for (int m = 32; m >= 1; m >>= 1) {
            float ov = __shfl_xor(v, m); int oc = __shfl_xor(c, m);
            if (ov > v || (ov == v && oc < c)) { v = ov; c = oc; }
        }
        #pragma unroll
        for (int j = 0; j < 4; ++j) if (c == lane + 64 * j) cv[j] = -INFINITY;
        int p = c >> 4, q = c & 15;
        int ex = __shfl(ai, p);
        int ey = __shfl(bi, q);
        if (lane == i) { myidx = ex * 128 + ey; myw = __expf(v); }
    }
    if (lane < 16) {
        oidx[t * TOPK + lane] = myidx;
        owt[t * TOPK + lane]  = myw;
    }
}

// ---------------- expert gather/combine (bf16 tables + bf16 x) ----------------
__global__ __launch_bounds__(256)
void expert_combine(const unsigned short* __restrict__ xb, const int* __restrict__ idx,
                    const float* __restrict__ wts, const unsigned short* __restrict__ ueb,
                    const unsigned short* __restrict__ deb, float* __restrict__ out) {
    const int t = blockIdx.x;
    const int tid = threadIdx.x;
    const int lane = tid & 63, wv = tid >> 6;
    __shared__ float part[TOPK * 4];
    __shared__ float sc[TOPK];
    ushort4 xv4 = ((const ushort4*)(xb + (size_t)t * HDIM))[tid];
    float x0 = bf2f(xv4.x), x1 = bf2f(xv4.y), x2 = bf2f(xv4.z), x3 = bf2f(xv4.w);
    int e[TOPK];
    #pragma unroll
    for (int k = 0; k < TOPK; ++k) e[k] = idx[t * TOPK + k];
    #pragma unroll
    for (int k = 0; k < TOPK; ++k) {
        ushort4 u4 = ((const ushort4*)(ueb + (size_t)e[k] * HDIM))[tid];
        float p = bf2f(u4.x) * x0 + bf2f(u4.y) * x1 + bf2f(u4.z) * x2 + bf2f(u4.w) * x3;
        #pragma unroll
        for (int m = 32; m >= 1; m >>= 1) p += __shfl_xor(p, m);
        if (lane == 0) part[k * 4 + wv] = p;
    }
    __syncthreads();
    if (tid < TOPK) {
        float s = part[tid * 4] + part[tid * 4 + 1] + part[tid * 4 + 2] + part[tid * 4 + 3];
        sc[tid] = s * wts[t * TOPK + tid];
    }
    __syncthreads();
    float4 acc = {0.f, 0.f, 0.f, 0.f};
    #pragma unroll
    for (int k = 0; k < TOPK; ++k) {
        float s = sc[k];
        ushort4 d4 = ((const ushort4*)(deb + (size_t)e[k] * HDIM))[tid];
        acc.x += s * bf2f(d4.x); acc.y += s * bf2f(d4.y);
        acc.z += s * bf2f(d4.z); acc.w += s * bf2f(d4.w);
    }
    ((float4*)(out + (size_t)t * HDIM))[tid] = acc;
}

extern "C" void kernel_launch(void* const* d_in, const int* in_sizes, int n_in,
                              void* d_out, int out_size, void* d_ws, size_t ws_size,
                              hipStream_t stream) {
    const float* x  = (const float*)d_in[0];
    const float* gw = (const float*)d_in[1];
    const float* uw = (const float*)d_in[2];
    const float* dw = (const float*)d_in[3];
    const float* wx = (const float*)d_in[4];
    const float* wy = (const float*)d_in[5];
    const float* ue = (const float*)d_in[6];
    const float* de = (const float*)d_in[7];
    float* out = (float*)d_out;

    char* ws = (char*)d_ws;
    size_t o = 0;
    auto alloc = [&](size_t bytes) { void* p = ws + o; o += (bytes + 255) & ~(size_t)255; return p; };
    unsigned short* xb    = (unsigned short*)alloc((size_t)T_TOK * HDIM * 2);
    unsigned short* gateb = (unsigned short*)alloc((size_t)IDIM * HDIM * 2);
    unsigned short* upb   = (unsigned short*)alloc((size_t)IDIM * HDIM * 2);
    unsigned short* downb = (unsigned short*)alloc((size_t)HDIM * IDIM * 2);
    unsigned short* wrb   = (unsigned short*)alloc((size_t)256 * HDIM * 2);
    unsigned short* ueb   = (unsigned short*)alloc((size_t)16384 * HDIM * 2);
    unsigned short* deb   = (unsigned short*)alloc((size_t)16384 * HDIM * 2);
    unsigned short* hbuf  = (unsigned short*)alloc((size_t)T_TOK * IDIM * 2);
    float* gxy  = (float*)alloc((size_t)T_TOK * 256 * 4);
    float* sums = (float*)alloc(256 * 4);
    float* ssq  = (float*)alloc(256 * 4);
    int*   idxs = (int*)alloc((size_t)T_TOK * TOPK * 4);
    float* wts  = (float*)alloc((size_t)T_TOK * TOPK * 4);

    // merged converts (8 segments)
    CvtSegs segs;
    const float* srcs[8] = {x, gw, uw, dw, wx, wy, ue, de};
    unsigned short* dsts[8] = {xb, gateb, upb, downb, wrb, wrb + SDIM * HDIM, ueb, deb};
    const int cnt4[8] = {T_TOK * HDIM / 4, IDIM * HDIM / 4, IDIM * HDIM / 4, IDIM * HDIM / 4,
                         SDIM * HDIM / 4, SDIM * HDIM / 4, 16384 * HDIM / 4, 16384 * HDIM / 4};
    int acc = 0;
    for (int i = 0; i < 8; ++i) {
        segs.src[i] = (const float4*)srcs[i];
        segs.dst[i] = (ushort4*)dsts[i];
        acc += cnt4[i];
        segs.end[i] = acc;
    }
    cvt_all_kernel<<<(acc + 255) / 256, 256, 0, stream>>>(segs);

    // router logits: gxy[T,256] = xb @ wrb^T
    hipMemsetAsync(sums, 0, 2 * 256 * 4, stream);  // sums+ssq contiguous
    gemm_bt<0><<<dim3(T_TOK / 128, 256 / 128), 256, 0, stream>>>(xb, wrb, gxy, T_TOK, 256, HDIM);
    bn_stats<<<256, 256, 0, stream>>>(gxy, sums, ssq);
    routing_kernel<<<T_TOK / 4, 256, 0, stream>>>(gxy, sums, ssq, idxs, wts);

    // expert branch writes out fully
    expert_combine<<<T_TOK, 256, 0, stream>>>(xb, idxs, wts, ueb, deb, out);

    // MLP branch: ring-4 fused gate/up GEMM, then ring-4 down-proj accumulate
    gemm1_8ph<<<1024, 512, 0, stream>>>(xb, gateb, upb, hbuf);
    gemm2_8ph<<<256, 512, 0, stream>>>(hbuf, downb, out);
}